// Round 2
// baseline (100.037 us; speedup 1.0000x reference)
//
#include <hip/hip_runtime.h>
#include <math.h>

#define NROWS 16384
#define DDIM  128
#define JCHUNK 512   // (t,e) pairs staged per block

__device__ __forceinline__ float wave_reduce_sum(float v) {
    #pragma unroll
    for (int m = 32; m >= 1; m >>= 1) v += __shfl_xor(v, m, 64);
    return v;
}

// ws layout (floats):
//   [0 .. N)       logits
//   [N .. 2N)      denom
//   [2N .. 4N)     te pairs: (time_j, exp(logit_j)) interleaved

// One wave per row: logits + exp + te pack. Proto norm recomputed per wave
// (free, VALU-parallel). First 64 blocks also zero denom for k_denom's atomics.
__global__ __launch_bounds__(256) void k_logits(
    const float* __restrict__ feats, const float* __restrict__ proto,
    const float* __restrict__ times,
    float* __restrict__ logits, float* __restrict__ te,
    float* __restrict__ denom)
{
    if (blockIdx.x < 64) denom[blockIdx.x * 256 + threadIdx.x] = 0.0f;
    int wave = threadIdx.x >> 6, lane = threadIdx.x & 63;
    int row = blockIdx.x * 4 + wave;   // one wave per row
    float2 f = ((const float2*)feats)[row * 64 + lane];
    float2 p = ((const float2*)proto)[lane];
    float d  = f.x * p.x + f.y * p.y;
    float n2 = f.x * f.x + f.y * f.y;
    float p2 = p.x * p.x + p.y * p.y;
    d  = wave_reduce_sum(d);
    n2 = wave_reduce_sum(n2);
    p2 = wave_reduce_sum(p2);
    if (lane == 0) {
        float invpn = 1.0f / fmaxf(sqrtf(p2), 1e-12f);
        float invfn = 1.0f / fmaxf(sqrtf(n2), 1e-12f);
        float logit = (d * invpn * invfn) / 0.07f;
        logits[row]     = logit;
        te[2 * row]     = times[row];
        te[2 * row + 1] = expf(logit);
    }
}

// denom[i] += sum over this block's j-chunk of e_j * (t_j >= t_i)
// grid (16 i-blocks of 1024 rows, 32 j-chunks of 512 pairs).
// 4 i-rows per thread: one broadcast ds_read_b128 feeds 8 cmp/sel/add.
__global__ __launch_bounds__(256) void k_denom(
    const float* __restrict__ times, const float* __restrict__ te,
    float* __restrict__ denom)
{
    __shared__ float4 sh[JCHUNK / 2];  // 256 float4 = 4 KB
    int t = threadIdx.x;
    const float4* src = (const float4*)(te + (size_t)blockIdx.y * JCHUNK * 2);
    sh[t] = src[t];
    int ibase = blockIdx.x * 1024 + t;
    float ti0 = times[ibase];
    float ti1 = times[ibase + 256];
    float ti2 = times[ibase + 512];
    float ti3 = times[ibase + 768];
    __syncthreads();
    float a0 = 0.f, a1 = 0.f, a2 = 0.f, a3 = 0.f;
    #pragma unroll 4
    for (int jj = 0; jj < JCHUNK / 2; ++jj) {
        float4 v = sh[jj];             // broadcast: conflict-free
        a0 += (v.x >= ti0) ? v.y : 0.0f;  a0 += (v.z >= ti0) ? v.w : 0.0f;
        a1 += (v.x >= ti1) ? v.y : 0.0f;  a1 += (v.z >= ti1) ? v.w : 0.0f;
        a2 += (v.x >= ti2) ? v.y : 0.0f;  a2 += (v.z >= ti2) ? v.w : 0.0f;
        a3 += (v.x >= ti3) ? v.y : 0.0f;  a3 += (v.z >= ti3) ? v.w : 0.0f;
    }
    atomicAdd(&denom[ibase],       a0);
    atomicAdd(&denom[ibase + 256], a1);
    atomicAdd(&denom[ibase + 512], a2);
    atomicAdd(&denom[ibase + 768], a3);
}

// Single block: loss reduction + final divide (avoids extra launch + atomics).
__global__ __launch_bounds__(1024) void k_loss_final(
    const float* __restrict__ logits, const float* __restrict__ denom,
    const int* __restrict__ events, const float* __restrict__ w,
    float* __restrict__ out)
{
    float ls = 0.f, wsum = 0.f;
    for (int i = threadIdx.x; i < NROWS; i += 1024) {
        float ev = (float)events[i];
        float wv = ev * w[i];
        ls   += -(logits[i] - logf(denom[i] + 1e-8f)) * wv;
        wsum += wv;
    }
    ls   = wave_reduce_sum(ls);
    wsum = wave_reduce_sum(wsum);
    __shared__ float s1[16], s2[16];
    int wave = threadIdx.x >> 6, lane = threadIdx.x & 63;
    if (lane == 0) { s1[wave] = ls; s2[wave] = wsum; }
    __syncthreads();
    if (threadIdx.x == 0) {
        float L = 0.f, W = 0.f;
        #pragma unroll
        for (int k = 0; k < 16; ++k) { L += s1[k]; W += s2[k]; }
        out[0] = L / (W + 1e-8f);
    }
}

extern "C" void kernel_launch(void* const* d_in, const int* in_sizes, int n_in,
                              void* d_out, int out_size, void* d_ws, size_t ws_size,
                              hipStream_t stream) {
    const float* feats  = (const float*)d_in[0];
    const float* times  = (const float*)d_in[1];
    const int*   events = (const int*)d_in[2];
    const float* w      = (const float*)d_in[3];
    const float* proto  = (const float*)d_in[4];
    float* out  = (float*)d_out;
    float* ws_f = (float*)d_ws;

    float* logits = ws_f;
    float* denom  = ws_f + NROWS;
    float* te     = ws_f + 2 * NROWS;

    k_logits<<<NROWS / 4, 256, 0, stream>>>(feats, proto, times, logits, te, denom);
    k_denom<<<dim3(NROWS / 1024, NROWS / JCHUNK), 256, 0, stream>>>(times, te, denom);
    k_loss_final<<<1, 1024, 0, stream>>>(logits, denom, events, w, out);
}